// Round 3
// baseline (100.346 us; speedup 1.0000x reference)
//
#include <hip/hip_runtime.h>

#define NQ 4
#define DIM 16

// Round 16: FUSE prep+main into one kernel. Evidence: R13 (delivery-pipe swap)
// = null, R15 (E=4 amortization) = regression -> main's internals are not the
// bottleneck; the two-dispatch serialization (prep fully drains before 4096
// main blocks start) is the only source-controllable fixed cost left.
// Every block redundantly builds H (phases 1-3, verified R1-R12) in LDS
// (~2us of <=100-thread work, overlapped across resident blocks), then runs
// the verified E=1 main body. Workspace no longer used.

typedef __attribute__((ext_vector_type(4))) float fv4;

constexpr int PA[10] = {0,0,0,0,1,1,1,2,2,3};
constexpr int PC[10] = {0,1,2,3,1,2,3,2,3,3};

// TC[ac][i]: coefficient (x1/4) of basis u_i (i = 3*i0+i1, f = {1, cos, sin})
// in hh_{PA[ac]} * hh_{PC[ac]}. Same matrix applies to the ll side (x2,x3).
__device__ constexpr float TC[10][9] = {
    {1, 1, 0,  1, 1, 0,  0, 0, 0},   // (0,0): (1+c0)(1+c1)
    {0, 0, 1,  0, 0, 1,  0, 0, 0},   // (0,1): (1+c0) s1
    {0, 0, 0,  0, 0, 0,  1, 1, 0},   // (0,2): s0 (1+c1)
    {0, 0, 0,  0, 0, 0,  0, 0, 1},   // (0,3): s0 s1
    {1,-1, 0,  1,-1, 0,  0, 0, 0},   // (1,1): (1+c0)(1-c1)
    {0, 0, 0,  0, 0, 0,  0, 0, 1},   // (1,2): s0 s1
    {0, 0, 0,  0, 0, 0,  1,-1, 0},   // (1,3): s0 (1-c1)
    {1, 1, 0, -1,-1, 0,  0, 0, 0},   // (2,2): (1-c0)(1+c1)
    {0, 0, 1,  0, 0,-1,  0, 0, 0},   // (2,3): (1-c0) s1
    {1,-1, 0, -1, 1, 0,  0, 0, 0},   // (3,3): (1-c0)(1-c1)
};

__global__ void __launch_bounds__(256)
qlayer_fused(const float4* __restrict__ x,
             const float*  __restrict__ weights,
             fv4* __restrict__ out, int B)
{
    __shared__ __align__(16) float2 WT[DIM][DIM];   // WT[j][i] = W[i][j]
    __shared__ __align__(16) fv4 G4[100];
    __shared__ __align__(16) fv4 H[81];

    const int tid = threadIdx.x;

    // ---- phase 1: threads 0..15 build W columns (verified R1-R12) ----
    if (tid < DIM) {
        const int k = tid;
        float sre[DIM], sim[DIM];
#pragma unroll
        for (int i = 0; i < DIM; ++i) { sre[i] = (i == k) ? 1.f : 0.f; sim[i] = 0.f; }
#pragma unroll
        for (int l = 0; l < 3; ++l) {
#pragma unroll
            for (int p = 0; p < NQ; ++p) {
                const float h = 0.5f * weights[l * NQ + p];
                const float s = __sinf(h), c = __cosf(h);
                const int mask = 1 << (NQ - 1 - p);
#pragma unroll
                for (int i = 0; i < DIM; ++i) {
                    if (i & mask) continue;
                    const int jj = i | mask;
                    const float ar = sre[i], ai = sim[i];
                    const float br = sre[jj], bi = sim[jj];
                    sre[i]  = c * ar + s * bi;
                    sim[i]  = c * ai - s * br;
                    sre[jj] = c * br + s * ai;
                    sim[jj] = c * bi - s * ar;
                }
            }
#pragma unroll
            for (int p = 0; p < NQ; ++p) {
                const int t = (p + 1) % NQ;
                float tr[DIM], ti[DIM];
#pragma unroll
                for (int i = 0; i < DIM; ++i) {
                    const int src = i ^ ((((i >> (NQ - 1 - p)) & 1)) << (NQ - 1 - t));
                    tr[i] = sre[src]; ti[i] = sim[src];
                }
#pragma unroll
                for (int i = 0; i < DIM; ++i) { sre[i] = tr[i]; sim[i] = ti[i]; }
            }
        }
#pragma unroll
        for (int i = 0; i < DIM; ++i) WT[k][i] = make_float2(sre[i], sim[i]);
    }
    __syncthreads();

    // ---- phase 2: threads 0..99 build folded G table (verified R2-R12) ----
    if (tid < 100) {
        const int ac = tid / 10, bd = tid % 10;
        const int a = PA[ac], c = PC[ac], b = PA[bd], d = PC[bd];

        auto evalS = [&](int j, int k, float* sv) {
            float ar[4] = {0,0,0,0}, ai[4] = {0,0,0,0};
#pragma unroll
            for (int i = 0; i < DIM; ++i) {
                const float2 wj = WT[j][i], wk = WT[k][i];
                const float pr = wj.x * wk.x + wj.y * wk.y;
                const float pi = wj.x * wk.y - wj.y * wk.x;
#pragma unroll
                for (int q = 0; q < 4; ++q) {
                    const float s = ((i >> (3 - q)) & 1) ? -1.f : 1.f;
                    ar[q] += s * pr; ai[q] += s * pi;
                }
            }
            const int m = (__builtin_popcount(j) - __builtin_popcount(k)) & 3;
#pragma unroll
            for (int q = 0; q < 4; ++q)
                sv[q] = (m == 0) ? ar[q] : (m == 1) ? -ai[q] : (m == 2) ? -ar[q] : ai[q];
        };

        float s1[4], s2[4];
        evalS(4 * a + b, 4 * c + d, s1);
        evalS(4 * a + d, 4 * c + b, s2);
        const float u = ((a < c) ? 2.f : 1.f) * ((b < d) ? 1.f : 0.5f);
        fv4 gv; gv.x = u*(s1[0]+s2[0]); gv.y = u*(s1[1]+s2[1]);
        gv.z = u*(s1[2]+s2[2]); gv.w = u*(s1[3]+s2[3]);
        G4[ac * 10 + bd] = gv;
    }
    __syncthreads();

    // ---- phase 3: threads 0..80 basis change H = (1/16) T G T^T (verified R12) ----
    if (tid < 81) {
        const int i = tid / 9, j = tid % 9;
        fv4 acc = (fv4)(0.f);
#pragma unroll
        for (int ac = 0; ac < 10; ++ac) {
            const float ti = TC[ac][i];
            fv4 tj = (fv4)(0.f);
#pragma unroll
            for (int bd = 0; bd < 10; ++bd)
                tj += G4[ac * 10 + bd] * TC[bd][j];
            acc += tj * ti;
        }
        H[i * 9 + j] = acc * 0.0625f;
    }
    __syncthreads();

    // ---- main: verified E=1 body (R13), H rows from LDS ----
    const int gi = blockIdx.x * 256 + tid;
    if (gi >= B) return;

    const float4 xv = x[gi];
    const float cx0 = __cosf(xv.x), sx0 = __sinf(xv.x);   // full angles
    const float cx1 = __cosf(xv.y), sx1 = __sinf(xv.y);
    const float cx2 = __cosf(xv.z), sx2 = __sinf(xv.z);
    const float cx3 = __cosf(xv.w), sx3 = __sinf(xv.w);

    float u[8], v[8];
    u[0] = cx1;       u[1] = sx1;       u[2] = cx0;
    u[3] = cx0 * cx1; u[4] = cx0 * sx1;
    u[5] = sx0;       u[6] = sx0 * cx1; u[7] = sx0 * sx1;
    v[0] = cx3;       v[1] = sx3;       v[2] = cx2;
    v[3] = cx2 * cx3; v[4] = cx2 * sx3;
    v[5] = sx2;       v[6] = sx2 * cx3; v[7] = sx2 * sx3;

    fv4 o = (fv4)(0.f);
#pragma unroll
    for (int i = 0; i < 9; ++i) {
        fv4 t = H[i * 9];                        // j = 0 (v_0 = 1)
#pragma unroll
        for (int j = 1; j < 9; ++j)
            t += H[i * 9 + j] * v[j - 1];
        o = (i == 0) ? t : o + t * u[i - 1];     // u_0 = 1
    }

    out[gi] = o;
}

extern "C" void kernel_launch(void* const* d_in, const int* in_sizes, int n_in,
                              void* d_out, int out_size, void* d_ws, size_t ws_size,
                              hipStream_t stream)
{
    const float4* x = (const float4*)d_in[0];
    const float* w  = (const float*)d_in[1];
    fv4* out        = (fv4*)d_out;
    const int B = in_sizes[0] / NQ;

    const int block = 256;
    const int grid = (B + block - 1) / block;
    qlayer_fused<<<grid, block, 0, stream>>>(x, w, out, B);
}

// Round 4
// 89.621 us; speedup vs baseline: 1.1197x; 1.1197x over previous
//
#include <hip/hip_runtime.h>

#define NQ 4
#define DIM 16

// Round 17: revert R16 fusion (regression: redundant per-block H prep,
// counters showed VALUBusy 29% / 60us). Root cause of main's ~30us now
// identified from R16 counters: VGPR=52 -> H (81 fv4 = 324 dwords) can never
// be register-resident, so every element pays a serialized H load->wait->FMA
// chain. Fix: split the 4 output components across threads (q = tid&3).
// Per-thread H slice = 81 floats -> register-resident, loaded once per
// kernel; grid-stride loop amortizes. Element loop = pure VALU + x/out
// streaming. Coalescing: 4 lanes share one x[e] float4 (256B/wave), lanes
// write 4 consecutive floats (256B/wave). Arithmetic per component is
// bit-identical to verified R13 -> absmax unchanged.

typedef __attribute__((ext_vector_type(4))) float fv4;

constexpr int PA[10] = {0,0,0,0,1,1,1,2,2,3};
constexpr int PC[10] = {0,1,2,3,1,2,3,2,3,3};

// TC[ac][i]: coefficient (x1/4) of basis u_i (i = 3*i0+i1, f = {1, cos, sin})
// in hh_{PA[ac]} * hh_{PC[ac]}. Same matrix applies to the ll side (x2,x3).
__device__ constexpr float TC[10][9] = {
    {1, 1, 0,  1, 1, 0,  0, 0, 0},   // (0,0): (1+c0)(1+c1)
    {0, 0, 1,  0, 0, 1,  0, 0, 0},   // (0,1): (1+c0) s1
    {0, 0, 0,  0, 0, 0,  1, 1, 0},   // (0,2): s0 (1+c1)
    {0, 0, 0,  0, 0, 0,  0, 0, 1},   // (0,3): s0 s1
    {1,-1, 0,  1,-1, 0,  0, 0, 0},   // (1,1): (1+c0)(1-c1)
    {0, 0, 0,  0, 0, 0,  0, 0, 1},   // (1,2): s0 s1
    {0, 0, 0,  0, 0, 0,  1,-1, 0},   // (1,3): s0 (1-c1)
    {1, 1, 0, -1,-1, 0,  0, 0, 0},   // (2,2): (1-c0)(1+c1)
    {0, 0, 1,  0, 0,-1,  0, 0, 0},   // (2,3): (1-c0) s1
    {1,-1, 0, -1, 1, 0,  0, 0, 0},   // (3,3): (1-c0)(1-c1)
};

__global__ void __launch_bounds__(128)
qlayer_prep(const float* __restrict__ weights, fv4* __restrict__ hw)
{
    __shared__ __align__(16) float2 WT[DIM][DIM];   // WT[j][i] = W[i][j]
    __shared__ __align__(16) fv4 G4[100];

    // ---- phase 1: threads 0..15 build W columns (verified R1-R12) ----
    if (threadIdx.x < DIM) {
        const int k = threadIdx.x;
        float sre[DIM], sim[DIM];
#pragma unroll
        for (int i = 0; i < DIM; ++i) { sre[i] = (i == k) ? 1.f : 0.f; sim[i] = 0.f; }
#pragma unroll
        for (int l = 0; l < 3; ++l) {
#pragma unroll
            for (int p = 0; p < NQ; ++p) {
                const float h = 0.5f * weights[l * NQ + p];
                const float s = __sinf(h), c = __cosf(h);
                const int mask = 1 << (NQ - 1 - p);
#pragma unroll
                for (int i = 0; i < DIM; ++i) {
                    if (i & mask) continue;
                    const int jj = i | mask;
                    const float ar = sre[i], ai = sim[i];
                    const float br = sre[jj], bi = sim[jj];
                    sre[i]  = c * ar + s * bi;
                    sim[i]  = c * ai - s * br;
                    sre[jj] = c * br + s * ai;
                    sim[jj] = c * bi - s * ar;
                }
            }
#pragma unroll
            for (int p = 0; p < NQ; ++p) {
                const int t = (p + 1) % NQ;
                float tr[DIM], ti[DIM];
#pragma unroll
                for (int i = 0; i < DIM; ++i) {
                    const int src = i ^ ((((i >> (NQ - 1 - p)) & 1)) << (NQ - 1 - t));
                    tr[i] = sre[src]; ti[i] = sim[src];
                }
#pragma unroll
                for (int i = 0; i < DIM; ++i) { sre[i] = tr[i]; sim[i] = ti[i]; }
            }
        }
#pragma unroll
        for (int i = 0; i < DIM; ++i) WT[k][i] = make_float2(sre[i], sim[i]);
    }
    __syncthreads();

    // ---- phase 2: threads 0..99 build folded G table (verified R2-R12) ----
    if (threadIdx.x < 100) {
        const int ac = threadIdx.x / 10, bd = threadIdx.x % 10;
        const int a = PA[ac], c = PC[ac], b = PA[bd], d = PC[bd];

        auto evalS = [&](int j, int k, float* sv) {
            float ar[4] = {0,0,0,0}, ai[4] = {0,0,0,0};
#pragma unroll
            for (int i = 0; i < DIM; ++i) {
                const float2 wj = WT[j][i], wk = WT[k][i];
                const float pr = wj.x * wk.x + wj.y * wk.y;
                const float pi = wj.x * wk.y - wj.y * wk.x;
#pragma unroll
                for (int q = 0; q < 4; ++q) {
                    const float s = ((i >> (3 - q)) & 1) ? -1.f : 1.f;
                    ar[q] += s * pr; ai[q] += s * pi;
                }
            }
            const int m = (__builtin_popcount(j) - __builtin_popcount(k)) & 3;
#pragma unroll
            for (int q = 0; q < 4; ++q)
                sv[q] = (m == 0) ? ar[q] : (m == 1) ? -ai[q] : (m == 2) ? -ar[q] : ai[q];
        };

        float s1[4], s2[4];
        evalS(4 * a + b, 4 * c + d, s1);
        evalS(4 * a + d, 4 * c + b, s2);
        const float u = ((a < c) ? 2.f : 1.f) * ((b < d) ? 1.f : 0.5f);
        fv4 gv; gv.x = u*(s1[0]+s2[0]); gv.y = u*(s1[1]+s2[1]);
        gv.z = u*(s1[2]+s2[2]); gv.w = u*(s1[3]+s2[3]);
        G4[ac * 10 + bd] = gv;
    }
    __syncthreads();

    // ---- phase 3: threads 0..80 basis change H = (1/16) T G T^T (verified R12) ----
    if (threadIdx.x < 81) {
        const int i = threadIdx.x / 9, j = threadIdx.x % 9;
        fv4 acc = (fv4)(0.f);
#pragma unroll
        for (int ac = 0; ac < 10; ++ac) {
            const float ti = TC[ac][i];
            fv4 tj = (fv4)(0.f);
#pragma unroll
            for (int bd = 0; bd < 10; ++bd)
                tj += G4[ac * 10 + bd] * TC[bd][j];
            acc += tj * ti;
        }
        hw[i * 9 + j] = acc * 0.0625f;
    }
}

__global__ void __launch_bounds__(256)
qlayer_main(const float4* __restrict__ x,
            const float* __restrict__ hwf,    // hw viewed as floats: hwf[idx*4+q]
            float* __restrict__ outf, int B)
{
    const int lin = blockIdx.x * 256 + threadIdx.x;
    const int q = lin & 3;                    // this thread's output component
    const int el0 = lin >> 2;
    const int el_stride = (gridDim.x * 256) >> 2;

    // One-time: this component's 81 H coefficients -> registers (static
    // indexing everywhere below, fully unrolled -> stays in VGPRs).
    float Hq[81];
#pragma unroll
    for (int t = 0; t < 81; ++t)
        Hq[t] = hwf[t * 4 + q];

    for (int el = el0; el < B; el += el_stride) {
        const float4 xv = x[el];
        const float cx0 = __cosf(xv.x), sx0 = __sinf(xv.x);   // full angles
        const float cx1 = __cosf(xv.y), sx1 = __sinf(xv.y);
        const float cx2 = __cosf(xv.z), sx2 = __sinf(xv.z);
        const float cx3 = __cosf(xv.w), sx3 = __sinf(xv.w);

        float u[8], v[8];
        u[0] = cx1;       u[1] = sx1;       u[2] = cx0;
        u[3] = cx0 * cx1; u[4] = cx0 * sx1;
        u[5] = sx0;       u[6] = sx0 * cx1; u[7] = sx0 * sx1;
        v[0] = cx3;       v[1] = sx3;       v[2] = cx2;
        v[3] = cx2 * cx3; v[4] = cx2 * sx3;
        v[5] = sx2;       v[6] = sx2 * cx3; v[7] = sx2 * sx3;

        float o = 0.f;
#pragma unroll
        for (int i = 0; i < 9; ++i) {
            float t = Hq[i * 9];                      // j = 0 (v_0 = 1)
#pragma unroll
            for (int j = 1; j < 9; ++j)
                t = fmaf(Hq[i * 9 + j], v[j - 1], t);
            o = (i == 0) ? t : fmaf(t, u[i - 1], o);  // u_0 = 1
        }

        outf[el * 4 + q] = o;
    }
}

extern "C" void kernel_launch(void* const* d_in, const int* in_sizes, int n_in,
                              void* d_out, int out_size, void* d_ws, size_t ws_size,
                              hipStream_t stream)
{
    const float4* x = (const float4*)d_in[0];
    const float* w  = (const float*)d_in[1];
    float* outf     = (float*)d_out;
    fv4* hw         = (fv4*)d_ws;     // 81 * 16 B = 1296 B
    const int B = in_sizes[0] / NQ;

    qlayer_prep<<<1, 128, 0, stream>>>(w, hw);

    const int grid = 2048;            // 512K threads = 128K elements/sweep
    qlayer_main<<<grid, 256, 0, stream>>>(x, (const float*)hw, outf, B);
}

// Round 6
// 80.069 us; speedup vs baseline: 1.2532x; 1.1193x over previous
//
#include <hip/hip_runtime.h>

#define NQ 4
#define DIM 16

// Round 19 (= R18 resubmit; R18 bench was an infra failure, no signal).
// Restore the verified R13 structure (prep + E=1 main, 80.1us; R15/R16/R17
// packing/fusion/q-split all regressed and are dead), with ONE
// mechanism-backed delta inside main: H delivery split across TWO pipes.
// Rows i=0..4 come from LDS (ds pipe, staged once per block, 720B); rows
// i=5..8 keep R13's uniform s_load path (scalar pipe). R11(all-LDS) ==
// R13(all-SMEM) == ~80 showed either pipe alone carries ~900cyc/wave-batch,
// comparable to the 752cyc VALU stream; splitting halves each pipe's load so
// delivery hides under VALU. Arithmetic order bit-identical to R13.
// Micro: nontemporal out store (write-once stream).

typedef __attribute__((ext_vector_type(4))) float fv4;

constexpr int PA[10] = {0,0,0,0,1,1,1,2,2,3};
constexpr int PC[10] = {0,1,2,3,1,2,3,2,3,3};

// TC[ac][i]: coefficient (x1/4) of basis u_i (i = 3*i0+i1, f = {1, cos, sin})
// in hh_{PA[ac]} * hh_{PC[ac]}. Same matrix applies to the ll side (x2,x3).
__device__ constexpr float TC[10][9] = {
    {1, 1, 0,  1, 1, 0,  0, 0, 0},   // (0,0): (1+c0)(1+c1)
    {0, 0, 1,  0, 0, 1,  0, 0, 0},   // (0,1): (1+c0) s1
    {0, 0, 0,  0, 0, 0,  1, 1, 0},   // (0,2): s0 (1+c1)
    {0, 0, 0,  0, 0, 0,  0, 0, 1},   // (0,3): s0 s1
    {1,-1, 0,  1,-1, 0,  0, 0, 0},   // (1,1): (1+c0)(1-c1)
    {0, 0, 0,  0, 0, 0,  0, 0, 1},   // (1,2): s0 s1
    {0, 0, 0,  0, 0, 0,  1,-1, 0},   // (1,3): s0 (1-c1)
    {1, 1, 0, -1,-1, 0,  0, 0, 0},   // (2,2): (1-c0)(1+c1)
    {0, 0, 1,  0, 0,-1,  0, 0, 0},   // (2,3): (1-c0) s1
    {1,-1, 0, -1, 1, 0,  0, 0, 0},   // (3,3): (1-c0)(1-c1)
};

__global__ void __launch_bounds__(128)
qlayer_prep(const float* __restrict__ weights, fv4* __restrict__ hw)
{
    __shared__ __align__(16) float2 WT[DIM][DIM];   // WT[j][i] = W[i][j]
    __shared__ __align__(16) fv4 G4[100];

    // ---- phase 1: threads 0..15 build W columns (verified R1-R12) ----
    if (threadIdx.x < DIM) {
        const int k = threadIdx.x;
        float sre[DIM], sim[DIM];
#pragma unroll
        for (int i = 0; i < DIM; ++i) { sre[i] = (i == k) ? 1.f : 0.f; sim[i] = 0.f; }
#pragma unroll
        for (int l = 0; l < 3; ++l) {
#pragma unroll
            for (int p = 0; p < NQ; ++p) {
                const float h = 0.5f * weights[l * NQ + p];
                const float s = __sinf(h), c = __cosf(h);
                const int mask = 1 << (NQ - 1 - p);
#pragma unroll
                for (int i = 0; i < DIM; ++i) {
                    if (i & mask) continue;
                    const int jj = i | mask;
                    const float ar = sre[i], ai = sim[i];
                    const float br = sre[jj], bi = sim[jj];
                    sre[i]  = c * ar + s * bi;
                    sim[i]  = c * ai - s * br;
                    sre[jj] = c * br + s * ai;
                    sim[jj] = c * bi - s * ar;
                }
            }
#pragma unroll
            for (int p = 0; p < NQ; ++p) {
                const int t = (p + 1) % NQ;
                float tr[DIM], ti[DIM];
#pragma unroll
                for (int i = 0; i < DIM; ++i) {
                    const int src = i ^ ((((i >> (NQ - 1 - p)) & 1)) << (NQ - 1 - t));
                    tr[i] = sre[src]; ti[i] = sim[src];
                }
#pragma unroll
                for (int i = 0; i < DIM; ++i) { sre[i] = tr[i]; sim[i] = ti[i]; }
            }
        }
#pragma unroll
        for (int i = 0; i < DIM; ++i) WT[k][i] = make_float2(sre[i], sim[i]);
    }
    __syncthreads();

    // ---- phase 2: threads 0..99 build folded G table (verified R2-R12) ----
    if (threadIdx.x < 100) {
        const int ac = threadIdx.x / 10, bd = threadIdx.x % 10;
        const int a = PA[ac], c = PC[ac], b = PA[bd], d = PC[bd];

        auto evalS = [&](int j, int k, float* sv) {
            float ar[4] = {0,0,0,0}, ai[4] = {0,0,0,0};
#pragma unroll
            for (int i = 0; i < DIM; ++i) {
                const float2 wj = WT[j][i], wk = WT[k][i];
                const float pr = wj.x * wk.x + wj.y * wk.y;
                const float pi = wj.x * wk.y - wj.y * wk.x;
#pragma unroll
                for (int q = 0; q < 4; ++q) {
                    const float s = ((i >> (3 - q)) & 1) ? -1.f : 1.f;
                    ar[q] += s * pr; ai[q] += s * pi;
                }
            }
            const int m = (__builtin_popcount(j) - __builtin_popcount(k)) & 3;
#pragma unroll
            for (int q = 0; q < 4; ++q)
                sv[q] = (m == 0) ? ar[q] : (m == 1) ? -ai[q] : (m == 2) ? -ar[q] : ai[q];
        };

        float s1[4], s2[4];
        evalS(4 * a + b, 4 * c + d, s1);
        evalS(4 * a + d, 4 * c + b, s2);
        const float u = ((a < c) ? 2.f : 1.f) * ((b < d) ? 1.f : 0.5f);
        fv4 gv; gv.x = u*(s1[0]+s2[0]); gv.y = u*(s1[1]+s2[1]);
        gv.z = u*(s1[2]+s2[2]); gv.w = u*(s1[3]+s2[3]);
        G4[ac * 10 + bd] = gv;
    }
    __syncthreads();

    // ---- phase 3: threads 0..80 basis change H = (1/16) T G T^T (verified R12) ----
    if (threadIdx.x < 81) {
        const int i = threadIdx.x / 9, j = threadIdx.x % 9;
        fv4 acc = (fv4)(0.f);
#pragma unroll
        for (int ac = 0; ac < 10; ++ac) {
            const float ti = TC[ac][i];
            fv4 tj = (fv4)(0.f);
#pragma unroll
            for (int bd = 0; bd < 10; ++bd)
                tj += G4[ac * 10 + bd] * TC[bd][j];
            acc += tj * ti;
        }
        hw[i * 9 + j] = acc * 0.0625f;
    }
}

__global__ void __launch_bounds__(256)
qlayer_main(const float4* __restrict__ x,
            const fv4* __restrict__ hw,
            fv4* __restrict__ out, int B)
{
    // Stage rows i=0..4 (45 fv4 = 720B) into LDS: these flow on the DS pipe.
    __shared__ __align__(16) fv4 HL[45];
    if (threadIdx.x < 45) HL[threadIdx.x] = hw[threadIdx.x];
    __syncthreads();

    const int gi = blockIdx.x * 256 + threadIdx.x;
    if (gi >= B) return;

    const float4 xv = x[gi];
    const float cx0 = __cosf(xv.x), sx0 = __sinf(xv.x);   // full angles
    const float cx1 = __cosf(xv.y), sx1 = __sinf(xv.y);
    const float cx2 = __cosf(xv.z), sx2 = __sinf(xv.z);
    const float cx3 = __cosf(xv.w), sx3 = __sinf(xv.w);

    float u[8], v[8];
    u[0] = cx1;       u[1] = sx1;       u[2] = cx0;
    u[3] = cx0 * cx1; u[4] = cx0 * sx1;
    u[5] = sx0;       u[6] = sx0 * cx1; u[7] = sx0 * sx1;
    v[0] = cx3;       v[1] = sx3;       v[2] = cx2;
    v[3] = cx2 * cx3; v[4] = cx2 * sx3;
    v[5] = sx2;       v[6] = sx2 * cx3; v[7] = sx2 * sx3;

    fv4 o = (fv4)(0.f);
    // Rows 0..4 from LDS (ds_read, uniform addr -> broadcast, no conflicts).
#pragma unroll
    for (int i = 0; i < 5; ++i) {
        fv4 t = HL[i * 9];                       // j = 0 (v_0 = 1)
#pragma unroll
        for (int j = 1; j < 9; ++j)
            t += HL[i * 9 + j] * v[j - 1];
        o = (i == 0) ? t : o + t * u[i - 1];     // u_0 = 1
    }
    // Rows 5..8 from global (uniform, read-only, __restrict__ -> s_load).
#pragma unroll
    for (int i = 5; i < 9; ++i) {
        fv4 t = hw[i * 9];
#pragma unroll
        for (int j = 1; j < 9; ++j)
            t += hw[i * 9 + j] * v[j - 1];
        o = o + t * u[i - 1];
    }

    __builtin_nontemporal_store(o, &out[gi]);
}

extern "C" void kernel_launch(void* const* d_in, const int* in_sizes, int n_in,
                              void* d_out, int out_size, void* d_ws, size_t ws_size,
                              hipStream_t stream)
{
    const float4* x = (const float4*)d_in[0];
    const float* w  = (const float*)d_in[1];
    fv4* out        = (fv4*)d_out;
    fv4* hw         = (fv4*)d_ws;     // 81 * 16 B = 1296 B
    const int B = in_sizes[0] / NQ;

    qlayer_prep<<<1, 128, 0, stream>>>(w, hw);

    const int block = 256;
    const int grid = (B + block - 1) / block;    // E=1 (verified structure)
    qlayer_main<<<grid, block, 0, stream>>>(x, hw, out, B);
}

// Round 8
// 79.256 us; speedup vs baseline: 1.2661x; 1.0103x over previous
//
#include <hip/hip_runtime.h>

#define NQ 4
#define DIM 16

// Round 21: RESTORE the verified best (R19 = 80.069us, passed). R20's coop
// single-launch failed correctness: harness poisons the 256MiB workspace
// grid-wide each iteration -> all 8 XCDs' L2s hold stale poison lines for hw;
// block 0's H writes + threadfence + grid.sync don't invalidate remote L2s
// (per-XCD L2 non-coherence, G16). Fixing it needs agent-scope atomics AND
// coop residency caps grid at 1024-2048 blocks -> forces E=2-4, the exact
// configs R15/R17 measured as +9-12us regressions. Single-launch lever closed.
// This kernel: prep + E=1 main, H delivery split LDS(rows 0-4)/SMEM(rows 5-8),
// nontemporal out store. Three-way delivery null (R11=R13=R19=80.07) + fixed
// harness costs (ws poison ~45us, out memset ~3us) => structural floor.

typedef __attribute__((ext_vector_type(4))) float fv4;

constexpr int PA[10] = {0,0,0,0,1,1,1,2,2,3};
constexpr int PC[10] = {0,1,2,3,1,2,3,2,3,3};

// TC[ac][i]: coefficient (x1/4) of basis u_i (i = 3*i0+i1, f = {1, cos, sin})
// in hh_{PA[ac]} * hh_{PC[ac]}. Same matrix applies to the ll side (x2,x3).
__device__ constexpr float TC[10][9] = {
    {1, 1, 0,  1, 1, 0,  0, 0, 0},   // (0,0): (1+c0)(1+c1)
    {0, 0, 1,  0, 0, 1,  0, 0, 0},   // (0,1): (1+c0) s1
    {0, 0, 0,  0, 0, 0,  1, 1, 0},   // (0,2): s0 (1+c1)
    {0, 0, 0,  0, 0, 0,  0, 0, 1},   // (0,3): s0 s1
    {1,-1, 0,  1,-1, 0,  0, 0, 0},   // (1,1): (1+c0)(1-c1)
    {0, 0, 0,  0, 0, 0,  0, 0, 1},   // (1,2): s0 s1
    {0, 0, 0,  0, 0, 0,  1,-1, 0},   // (1,3): s0 (1-c1)
    {1, 1, 0, -1,-1, 0,  0, 0, 0},   // (2,2): (1-c0)(1+c1)
    {0, 0, 1,  0, 0,-1,  0, 0, 0},   // (2,3): (1-c0) s1
    {1,-1, 0, -1, 1, 0,  0, 0, 0},   // (3,3): (1-c0)(1-c1)
};

__global__ void __launch_bounds__(128)
qlayer_prep(const float* __restrict__ weights, fv4* __restrict__ hw)
{
    __shared__ __align__(16) float2 WT[DIM][DIM];   // WT[j][i] = W[i][j]
    __shared__ __align__(16) fv4 G4[100];

    // ---- phase 1: threads 0..15 build W columns (verified R1-R12) ----
    if (threadIdx.x < DIM) {
        const int k = threadIdx.x;
        float sre[DIM], sim[DIM];
#pragma unroll
        for (int i = 0; i < DIM; ++i) { sre[i] = (i == k) ? 1.f : 0.f; sim[i] = 0.f; }
#pragma unroll
        for (int l = 0; l < 3; ++l) {
#pragma unroll
            for (int p = 0; p < NQ; ++p) {
                const float h = 0.5f * weights[l * NQ + p];
                const float s = __sinf(h), c = __cosf(h);
                const int mask = 1 << (NQ - 1 - p);
#pragma unroll
                for (int i = 0; i < DIM; ++i) {
                    if (i & mask) continue;
                    const int jj = i | mask;
                    const float ar = sre[i], ai = sim[i];
                    const float br = sre[jj], bi = sim[jj];
                    sre[i]  = c * ar + s * bi;
                    sim[i]  = c * ai - s * br;
                    sre[jj] = c * br + s * ai;
                    sim[jj] = c * bi - s * ar;
                }
            }
#pragma unroll
            for (int p = 0; p < NQ; ++p) {
                const int t = (p + 1) % NQ;
                float tr[DIM], ti[DIM];
#pragma unroll
                for (int i = 0; i < DIM; ++i) {
                    const int src = i ^ ((((i >> (NQ - 1 - p)) & 1)) << (NQ - 1 - t));
                    tr[i] = sre[src]; ti[i] = sim[src];
                }
#pragma unroll
                for (int i = 0; i < DIM; ++i) { sre[i] = tr[i]; sim[i] = ti[i]; }
            }
        }
#pragma unroll
        for (int i = 0; i < DIM; ++i) WT[k][i] = make_float2(sre[i], sim[i]);
    }
    __syncthreads();

    // ---- phase 2: threads 0..99 build folded G table (verified R2-R12) ----
    if (threadIdx.x < 100) {
        const int ac = threadIdx.x / 10, bd = threadIdx.x % 10;
        const int a = PA[ac], c = PC[ac], b = PA[bd], d = PC[bd];

        auto evalS = [&](int j, int k, float* sv) {
            float ar[4] = {0,0,0,0}, ai[4] = {0,0,0,0};
#pragma unroll
            for (int i = 0; i < DIM; ++i) {
                const float2 wj = WT[j][i], wk = WT[k][i];
                const float pr = wj.x * wk.x + wj.y * wk.y;
                const float pi = wj.x * wk.y - wj.y * wk.x;
#pragma unroll
                for (int q = 0; q < 4; ++q) {
                    const float s = ((i >> (3 - q)) & 1) ? -1.f : 1.f;
                    ar[q] += s * pr; ai[q] += s * pi;
                }
            }
            const int m = (__builtin_popcount(j) - __builtin_popcount(k)) & 3;
#pragma unroll
            for (int q = 0; q < 4; ++q)
                sv[q] = (m == 0) ? ar[q] : (m == 1) ? -ai[q] : (m == 2) ? -ar[q] : ai[q];
        };

        float s1[4], s2[4];
        evalS(4 * a + b, 4 * c + d, s1);
        evalS(4 * a + d, 4 * c + b, s2);
        const float u = ((a < c) ? 2.f : 1.f) * ((b < d) ? 1.f : 0.5f);
        fv4 gv; gv.x = u*(s1[0]+s2[0]); gv.y = u*(s1[1]+s2[1]);
        gv.z = u*(s1[2]+s2[2]); gv.w = u*(s1[3]+s2[3]);
        G4[ac * 10 + bd] = gv;
    }
    __syncthreads();

    // ---- phase 3: threads 0..80 basis change H = (1/16) T G T^T (verified R12) ----
    if (threadIdx.x < 81) {
        const int i = threadIdx.x / 9, j = threadIdx.x % 9;
        fv4 acc = (fv4)(0.f);
#pragma unroll
        for (int ac = 0; ac < 10; ++ac) {
            const float ti = TC[ac][i];
            fv4 tj = (fv4)(0.f);
#pragma unroll
            for (int bd = 0; bd < 10; ++bd)
                tj += G4[ac * 10 + bd] * TC[bd][j];
            acc += tj * ti;
        }
        hw[i * 9 + j] = acc * 0.0625f;
    }
}

__global__ void __launch_bounds__(256)
qlayer_main(const float4* __restrict__ x,
            const fv4* __restrict__ hw,
            fv4* __restrict__ out, int B)
{
    // Stage rows i=0..4 (45 fv4 = 720B) into LDS: these flow on the DS pipe.
    __shared__ __align__(16) fv4 HL[45];
    if (threadIdx.x < 45) HL[threadIdx.x] = hw[threadIdx.x];
    __syncthreads();

    const int gi = blockIdx.x * 256 + threadIdx.x;
    if (gi >= B) return;

    const float4 xv = x[gi];
    const float cx0 = __cosf(xv.x), sx0 = __sinf(xv.x);   // full angles
    const float cx1 = __cosf(xv.y), sx1 = __sinf(xv.y);
    const float cx2 = __cosf(xv.z), sx2 = __sinf(xv.z);
    const float cx3 = __cosf(xv.w), sx3 = __sinf(xv.w);

    float u[8], v[8];
    u[0] = cx1;       u[1] = sx1;       u[2] = cx0;
    u[3] = cx0 * cx1; u[4] = cx0 * sx1;
    u[5] = sx0;       u[6] = sx0 * cx1; u[7] = sx0 * sx1;
    v[0] = cx3;       v[1] = sx3;       v[2] = cx2;
    v[3] = cx2 * cx3; v[4] = cx2 * sx3;
    v[5] = sx2;       v[6] = sx2 * cx3; v[7] = sx2 * sx3;

    fv4 o = (fv4)(0.f);
    // Rows 0..4 from LDS (ds_read, uniform addr -> broadcast, no conflicts).
#pragma unroll
    for (int i = 0; i < 5; ++i) {
        fv4 t = HL[i * 9];                       // j = 0 (v_0 = 1)
#pragma unroll
        for (int j = 1; j < 9; ++j)
            t += HL[i * 9 + j] * v[j - 1];
        o = (i == 0) ? t : o + t * u[i - 1];     // u_0 = 1
    }
    // Rows 5..8 from global (uniform, read-only, __restrict__ -> s_load).
#pragma unroll
    for (int i = 5; i < 9; ++i) {
        fv4 t = hw[i * 9];
#pragma unroll
        for (int j = 1; j < 9; ++j)
            t += hw[i * 9 + j] * v[j - 1];
        o = o + t * u[i - 1];
    }

    __builtin_nontemporal_store(o, &out[gi]);
}

extern "C" void kernel_launch(void* const* d_in, const int* in_sizes, int n_in,
                              void* d_out, int out_size, void* d_ws, size_t ws_size,
                              hipStream_t stream)
{
    const float4* x = (const float4*)d_in[0];
    const float* w  = (const float*)d_in[1];
    fv4* out        = (fv4*)d_out;
    fv4* hw         = (fv4*)d_ws;     // 81 * 16 B = 1296 B
    const int B = in_sizes[0] / NQ;

    qlayer_prep<<<1, 128, 0, stream>>>(w, hw);

    const int block = 256;
    const int grid = (B + block - 1) / block;    // E=1 (verified structure)
    qlayer_main<<<grid, block, 0, stream>>>(x, hw, out, B);
}